// Round 6
// baseline (370.137 us; speedup 1.0000x reference)
//
#include <hip/hip_runtime.h>
#include <hip/hip_bf16.h>

// Problem constants (fixed by the reference)
#define Bq   2
#define S_   4096
#define E_   1024
#define H_   16
#define DK_  64
#define BS_  128
#define NB_  32           // S/BS
#define FDIM 1024         // H*DK == E
#define PPAD 264          // padded 256-key row (528 B)

typedef __attribute__((ext_vector_type(8))) short short8;   // 8 bf16 (4 VGPR)
typedef __attribute__((ext_vector_type(4))) float floatx4;

__device__ __forceinline__ float bf2f(unsigned short u) {
    union { unsigned int i; float f; } v; v.i = ((unsigned int)u) << 16; return v.f;
}
__device__ __forceinline__ unsigned short f2bf(float f) {
    union { float f; unsigned int i; } v; v.f = f;
    unsigned int x = v.i;
    return (unsigned short)((x + 0x7FFFu + ((x >> 16) & 1u)) >> 16);
}
__device__ __forceinline__ void gload_lds16(const void* g, void* l) {
    __builtin_amdgcn_global_load_lds(
        (const __attribute__((address_space(1))) unsigned int*)g,
        (__attribute__((address_space(3))) unsigned int*)l, 16, 0, 0);
}

// ---------------------------------------------------------------------------
// f32 -> bf16 bulk convert (8 elems/thread)
// ---------------------------------------------------------------------------
__global__ __launch_bounds__(256) void cvt_bf16(
    const float* __restrict__ src, unsigned short* __restrict__ dst, int n8)
{
    int i = blockIdx.x * 256 + threadIdx.x;
    if (i >= n8) return;
    float4 v0 = *(const float4*)(src + (size_t)i * 8);
    float4 v1 = *(const float4*)(src + (size_t)i * 8 + 4);
    unsigned short u[8];
    u[0] = f2bf(v0.x); u[1] = f2bf(v0.y); u[2] = f2bf(v0.z); u[3] = f2bf(v0.w);
    u[4] = f2bf(v1.x); u[5] = f2bf(v1.y); u[6] = f2bf(v1.z); u[7] = f2bf(v1.w);
    *(uint4*)(dst + (size_t)i * 8) = *(uint4*)u;
}

// ---------------------------------------------------------------------------
// bf16 transpose: KVt[b][d][s] = KVb[b][s][d]   (64x64 tiles via LDS)
// ---------------------------------------------------------------------------
__global__ __launch_bounds__(256) void transpose_kv(
    const unsigned short* __restrict__ in, unsigned short* __restrict__ out)
{
    __shared__ unsigned short T[64][68];
    const int b = blockIdx.z, s0 = blockIdx.x * 64, d0 = blockIdx.y * 64;
    const int t = threadIdx.x, r = t >> 4, c4 = (t & 15) * 4;
#pragma unroll
    for (int rr = 0; rr < 4; ++rr) {
        int sl = rr * 16 + r;
        *(ushort4*)(&T[sl][c4]) =
            *(const ushort4*)(in + ((size_t)(b * S_ + s0 + sl)) * FDIM + d0 + c4);
    }
    __syncthreads();
#pragma unroll
    for (int rr = 0; rr < 4; ++rr) {
        int dl = rr * 16 + r;
        ushort4 v;
        v.x = T[c4 + 0][dl]; v.y = T[c4 + 1][dl];
        v.z = T[c4 + 2][dl]; v.w = T[c4 + 3][dl];
        *(ushort4*)(out + ((size_t)(b * FDIM + d0 + dl)) * S_ + s0 + c4) = v;
    }
}

// ---------------------------------------------------------------------------
// m97-style GEMM: C[M,N] = A[M,K] @ B[N,K]^T, bf16 in, f32 acc.
// 128x128 tile, BK=32, 4 waves (2x2), global_load_lds width-16 staging.
// ---------------------------------------------------------------------------
template<bool C_F32>
__global__ __launch_bounds__(256) void gemm128(
    const unsigned short* __restrict__ A,
    const unsigned short* __restrict__ Bm,
    void* __restrict__ Cv, int M, int N, int K)
{
    __shared__ unsigned short As[128 * 32];   // 8 KB, row-major [128][32]
    __shared__ unsigned short Bs[128 * 32];   // 8 KB

    const int t    = threadIdx.x;
    const int lane = t & 63;
    const int wid  = t >> 6;
    const int row0 = blockIdx.x * 128;
    const int col0 = blockIdx.y * 128;

    const int srow0 = wid * 32 + (lane >> 2);     // + j*16
    const int scolE = (lane & 3) * 8;

    const int wr = wid >> 1, wc = wid & 1;
    const int lr = lane & 15, lj = lane >> 4;

    floatx4 acc[4][4];
#pragma unroll
    for (int m = 0; m < 4; ++m)
#pragma unroll
        for (int n = 0; n < 4; ++n) acc[m][n] = floatx4{0.f, 0.f, 0.f, 0.f};

    for (int k0 = 0; k0 < K; k0 += 32) {
#pragma unroll
        for (int j = 0; j < 2; ++j) {
            gload_lds16(A + (size_t)(row0 + srow0 + j * 16) * K + k0 + scolE,
                        (char*)As + (wid * 2 + j) * 1024);
            gload_lds16(Bm + (size_t)(col0 + srow0 + j * 16) * K + k0 + scolE,
                        (char*)Bs + (wid * 2 + j) * 1024);
        }
        __syncthreads();

        short8 a[4], b[4];
#pragma unroll
        for (int m = 0; m < 4; ++m)
            a[m] = *(const short8*)(As + (wr * 64 + m * 16 + lr) * 32 + lj * 8);
#pragma unroll
        for (int n = 0; n < 4; ++n)
            b[n] = *(const short8*)(Bs + (wc * 64 + n * 16 + lr) * 32 + lj * 8);
#pragma unroll
        for (int m = 0; m < 4; ++m)
#pragma unroll
            for (int n = 0; n < 4; ++n)
                acc[m][n] = __builtin_amdgcn_mfma_f32_16x16x32_bf16(a[m], b[n], acc[m][n], 0, 0, 0);
        __syncthreads();
    }

#pragma unroll
    for (int m = 0; m < 4; ++m) {
        const int crow = row0 + wr * 64 + m * 16 + lj * 4;
#pragma unroll
        for (int n = 0; n < 4; ++n) {
            const int ccol = col0 + wc * 64 + n * 16 + lr;
#pragma unroll
            for (int i = 0; i < 4; ++i) {
                if constexpr (C_F32)
                    ((float*)Cv)[(size_t)(crow + i) * N + ccol] = acc[m][n][i];
                else
                    ((unsigned short*)Cv)[(size_t)(crow + i) * N + ccol] = f2bf(acc[m][n][i]);
            }
        }
    }
}

// ---------------------------------------------------------------------------
// Fused blockwise talking-heads attention (MFMA), v3:
//  Round-4 math (e -> Z -> normalize+Ta mix in LDS -> diagonal PV), but with
//  16 waves/block (1024 thr): full 256-key window in one pass, 4 waves/SIMD.
//  Wave w owns k-tile w (QK) and head w (PV).
// Block = (n, qt, b): grid.x = n keeps window-sharing blocks on one XCD.
// ---------------------------------------------------------------------------
#define EL_BYTES (256 * PPAD * 2)            // 135168
#define TBT_OFF  EL_BYTES                    // 256 f32: Tb^T  [h][g]
#define TAL_OFF  (TBT_OFF + 1024)            // 256 f32: Ta    [gp][g]
#define RS_OFF   (TAL_OFF + 1024)            // 16 f32
#define IZ_OFF   (RS_OFF + 64)               // 256 f32
#define SMEM_SZ  (IZ_OFF + 1024)             // 138304

__global__ __launch_bounds__(1024, 4) void attn_fused(
    const unsigned short* __restrict__ Qb,
    const unsigned short* __restrict__ KVb,
    const unsigned short* __restrict__ KVt,
    const float* __restrict__ Tb,
    const float* __restrict__ Ta,
    unsigned short* __restrict__ ATTN)
{
    extern __shared__ char smem[];
    unsigned short* EL = (unsigned short*)smem;
    float* TBT = (float*)(smem + TBT_OFF);
    float* TAL = (float*)(smem + TAL_OFF);
    float* RS  = (float*)(smem + RS_OFF);
    float* IZ  = (float*)(smem + IZ_OFF);

    const int t = threadIdx.x;
    const int lane = t & 63, w = t >> 6;            // w in [0,16)
    const int lr = lane & 15, lj = lane >> 4;
    const int n = blockIdx.x, qt = blockIdx.y, b = blockIdx.z;
    const int q0 = n * BS_ + qt * 16;

    if (t < 256)      TBT[(t & 15) * 16 + (t >> 4)] = Tb[t];   // TBT[h][g]
    else if (t < 512) TAL[t - 256] = Ta[t - 256];
    else if (t < 528) {
        int g = t - 512;
        float s = 0.f;
#pragma unroll
        for (int h = 0; h < 16; ++h) s += Tb[g * 16 + h];
        RS[g] = s;
    }
    __syncthreads();

    // ---- Phase 1: QK^T + Tb mix + decay/bias + exp(s-12) -> EL --------------
    const int kpos0 = n * BS_ - BS_ + w * 16;
    const bool act = (kpos0 >= 0) && (w <= qt + 8);
    const unsigned short* Qrow = Qb + ((size_t)(b * S_ + q0 + lr)) * FDIM + lj * 8;

    if (act) {
        const unsigned short* Krow =
            KVb + ((size_t)(b * S_ + kpos0 + lr)) * FDIM + lj * 8;
        floatx4 mix[16];
#pragma unroll
        for (int g = 0; g < 16; ++g) mix[g] = floatx4{0.f, 0.f, 0.f, 0.f};
#pragma unroll 1
        for (int h = 0; h < 16; ++h) {
            floatx4 r = {0.f, 0.f, 0.f, 0.f};
            r = __builtin_amdgcn_mfma_f32_16x16x32_bf16(
                    *(const short8*)(Qrow + h * 64),
                    *(const short8*)(Krow + h * 64), r, 0, 0, 0);
            r = __builtin_amdgcn_mfma_f32_16x16x32_bf16(
                    *(const short8*)(Qrow + h * 64 + 32),
                    *(const short8*)(Krow + h * 64 + 32), r, 0, 0, 0);
#pragma unroll
            for (int g4 = 0; g4 < 4; ++g4) {
                float4 tb = *(const float4*)(TBT + h * 16 + g4 * 4);
                mix[g4 * 4 + 0] += tb.x * r;
                mix[g4 * 4 + 1] += tb.y * r;
                mix[g4 * 4 + 2] += tb.z * r;
                mix[g4 * 4 + 3] += tb.w * r;
            }
        }
        const int kpos = kpos0 + lr;
        const int qa = q0 + lj * 4;
#pragma unroll
        for (int g = 0; g < 16; ++g) {
            float rsg = RS[g];
#pragma unroll
            for (int i = 0; i < 4; ++i) {
                int diff = qa + i - kpos;
                float ad = fabsf((float)diff);
                float wd = 0.125f / (1.0f + 0.1f * ad);      // 1/sqrt(64) folded
                float sv = wd * mix[g][i] - (diff > 0 ? rsg : 0.f);
                float e  = (diff >= 0) ? exp2f((sv - 12.f) * 1.44269504f) : 0.f;
                EL[(g * 16 + lj * 4 + i) * PPAD + w * 16 + lr] = f2bf(e);
            }
        }
    } else {
#pragma unroll
        for (int g = 0; g < 16; ++g)
#pragma unroll
            for (int i = 0; i < 4; ++i)
                EL[(g * 16 + lj * 4 + i) * PPAD + w * 16 + lr] = 0;
    }
    __syncthreads();

    // ---- Phase 2: Z from EL readback; IZ = 1/Z -------------------------------
    if (t < 256) {
        const unsigned short* rp = EL + t * PPAD;
        float z = 0.f;
#pragma unroll 1
        for (int kk = 0; kk < 32; ++kk) {
            short8 v = *(const short8*)(rp + kk * 8);
#pragma unroll
            for (int j = 0; j < 8; ++j) z += bf2f((unsigned short)v[j]);
        }
        IZ[t] = 1.0f / z;
    }
    __syncthreads();

    // ---- Phase 3: normalize + Ta mix, in place (thread owns key w*16+lr) ----
    {
        const int krel = w * 16 + lr;
        float pz[16][4];
#pragma unroll
        for (int g = 0; g < 16; ++g)
#pragma unroll
            for (int i = 0; i < 4; ++i)
                pz[g][i] = bf2f(EL[(g * 16 + lj * 4 + i) * PPAD + krel]) *
                           IZ[g * 16 + lj * 4 + i];
#pragma unroll 1
        for (int gp = 0; gp < 16; ++gp) {
            float ta[16];
            *(float4*)(ta + 0)  = *(const float4*)(TAL + gp * 16 + 0);
            *(float4*)(ta + 4)  = *(const float4*)(TAL + gp * 16 + 4);
            *(float4*)(ta + 8)  = *(const float4*)(TAL + gp * 16 + 8);
            *(float4*)(ta + 12) = *(const float4*)(TAL + gp * 16 + 12);
#pragma unroll
            for (int i = 0; i < 4; ++i) {
                float v = 0.f;
#pragma unroll
                for (int g = 0; g < 16; ++g) v += ta[g] * pz[g][i];
                EL[(gp * 16 + lj * 4 + i) * PPAD + krel] = f2bf(v);
            }
        }
    }
    __syncthreads();

    // ---- Phase 4: PV. Wave w owns head gp=w: out[q,d] += P[q,k] @ V^T[d,k] ---
    floatx4 o[4];
#pragma unroll
    for (int nt = 0; nt < 4; ++nt) o[nt] = floatx4{0.f, 0.f, 0.f, 0.f};

    const int gp = w;
    const int ks_min = (n == 0) ? 4 : 0;
    const int ks_max = (143 + qt * 16) >> 5;     // inclusive
    for (int ks = ks_min; ks <= ks_max; ++ks) {
        const int kb = n * BS_ - BS_ + ks * 32 + lj * 8;
        short8 a = *(const short8*)(EL + (gp * 16 + lr) * PPAD + ks * 32 + lj * 8);
#pragma unroll
        for (int nt = 0; nt < 4; ++nt) {
            short8 vb = *(const short8*)(KVt +
                ((size_t)(b * FDIM + gp * 64 + nt * 16 + lr)) * S_ + kb);
            o[nt] = __builtin_amdgcn_mfma_f32_16x16x32_bf16(a, vb, o[nt], 0, 0, 0);
        }
    }

    unsigned short* obase = ATTN + ((size_t)(b * S_ + q0)) * FDIM;
#pragma unroll
    for (int nt = 0; nt < 4; ++nt)
#pragma unroll
        for (int i = 0; i < 4; ++i)
            obase[(size_t)(lj * 4 + i) * FDIM + gp * 64 + nt * 16 + lr] =
                f2bf(o[nt][i]);
}

// ---------------------------------------------------------------------------
extern "C" void kernel_launch(void* const* d_in, const int* in_sizes, int n_in,
                              void* d_out, int out_size, void* d_ws, size_t ws_size,
                              hipStream_t stream) {
    // inputs (f32): x, q_mask, Wq, Wk, Wo, Tb, Ta, rel_a, abs_a
    const float* x  = (const float*)d_in[0];
    const float* Wq = (const float*)d_in[2];
    const float* Wk = (const float*)d_in[3];
    const float* Wo = (const float*)d_in[4];
    const float* Tb = (const float*)d_in[5];
    const float* Ta = (const float*)d_in[6];
    float* out = (float*)d_out;

    const size_t MS = (size_t)Bq * S_;                 // 8192
    unsigned short* ws0 = (unsigned short*)d_ws;
    unsigned short* xb  = ws0;                          // aliased by ATTN later
    unsigned short* Qb  = ws0 + 1 * 8388608;
    unsigned short* KVb = ws0 + 2 * 8388608;
    unsigned short* KVt = ws0 + 3 * 8388608;
    unsigned short* Wqb = ws0 + 4 * 8388608;
    unsigned short* Wkb = Wqb + 1048576;
    unsigned short* Wob = Wkb + 1048576;
    unsigned short* ATTN = xb;                          // xb dead after projections

    cvt_bf16<<<dim3(4096), dim3(256), 0, stream>>>(x,  xb,  1048576);
    cvt_bf16<<<dim3(512),  dim3(256), 0, stream>>>(Wq, Wqb, 131072);
    cvt_bf16<<<dim3(512),  dim3(256), 0, stream>>>(Wk, Wkb, 131072);
    cvt_bf16<<<dim3(512),  dim3(256), 0, stream>>>(Wo, Wob, 131072);

    dim3 gg(64, 8), gb(256);
    gemm128<false><<<gg, gb, 0, stream>>>(xb, Wqb, Qb,  (int)MS, FDIM, E_);
    gemm128<false><<<gg, gb, 0, stream>>>(xb, Wkb, KVb, (int)MS, FDIM, E_);

    transpose_kv<<<dim3(64, 16, Bq), dim3(256), 0, stream>>>(KVb, KVt);

    (void)hipFuncSetAttribute((const void*)attn_fused,
                              hipFuncAttributeMaxDynamicSharedMemorySize, SMEM_SZ);
    attn_fused<<<dim3(NB_, 8, Bq), dim3(1024), SMEM_SZ, stream>>>(
        Qb, KVb, KVt, Tb, Ta, ATTN);

    gemm128<true><<<gg, gb, 0, stream>>>(ATTN, Wob, out, (int)MS, FDIM, E_);
}